// Round 6
// baseline (221.389 us; speedup 1.0000x reference)
//
#include <hip/hip_runtime.h>
#include <math.h>

#define NUM_CLASSES 100000
#define EMB 512
#define BATCH 512
#define BN 64
#define NBLK ((NUM_CLASSES + BN - 1) / BN)   /* 1563 chunks of 64 classes */
#define GRID_MAIN 256                        /* persistent, 1 block/CU */

// ArcFace constants (margin m=0.3, scale s=120)
#define S_SCALE 120.0f
#define COS_M   0.9553364891256061f
#define SIN_M   0.29552020666133955f
#define TH_C   (-0.9553364891256061f)        /* cos(pi - m) */
#define MM_C    0.08865606199840187f         /* sin(pi - m) * m */

typedef short bf8 __attribute__((ext_vector_type(8)));   // 8 x bf16 (4 VGPRs)
typedef float f4  __attribute__((ext_vector_type(4)));   // MFMA accumulator

__device__ __forceinline__ unsigned short f2bf(float f) {
    union { float f; unsigned u; } a; a.f = f;
    unsigned r = a.u + 0x7fffu + ((a.u >> 16) & 1u);     // round-nearest-even
    return (unsigned short)(r >> 16);
}

// ---------------------------------------------------------------------------
// Kernel 1: L2-normalize rows of x (f32) -> bf16, one wave per row.
// ---------------------------------------------------------------------------
__global__ __launch_bounds__(256) void k_normx(const float* __restrict__ x,
                                               unsigned short* __restrict__ xb) {
    int row  = blockIdx.x * 4 + (threadIdx.x >> 6);
    int lane = threadIdx.x & 63;
    const float4* xr = (const float4*)(x + (size_t)row * EMB);
    float4 a = xr[lane * 2];
    float4 b = xr[lane * 2 + 1];
    float ss = a.x*a.x + a.y*a.y + a.z*a.z + a.w*a.w
             + b.x*b.x + b.y*b.y + b.z*b.z + b.w*b.w;
#pragma unroll
    for (int d = 1; d < 64; d <<= 1) ss += __shfl_xor(ss, d);
    float rn = 1.0f / fmaxf(sqrtf(ss), 1e-12f);
    int4 o;
    o.x = f2bf(a.x * rn) | (f2bf(a.y * rn) << 16);
    o.y = f2bf(a.z * rn) | (f2bf(a.w * rn) << 16);
    o.z = f2bf(b.x * rn) | (f2bf(b.y * rn) << 16);
    o.w = f2bf(b.z * rn) | (f2bf(b.w * rn) << 16);
    ((int4*)(xb + (size_t)row * EMB))[lane] = o;
}

// ---------------------------------------------------------------------------
// Kernel 2: exact f32 target logit per row: s*cos and s*phi at the label.
// One wave per row.
// ---------------------------------------------------------------------------
__global__ __launch_bounds__(512) void k_tgt(const float* __restrict__ x,
                                             const float* __restrict__ W,
                                             const long long* __restrict__ label,
                                             float* __restrict__ tcos,
                                             float* __restrict__ tphi) {
    int m    = blockIdx.x * 8 + (threadIdx.x >> 6);
    int lane = threadIdx.x & 63;
    int lb   = (int)label[m];
    const float4* xr = (const float4*)(x + (size_t)m  * EMB);
    const float4* wr = (const float4*)(W + (size_t)lb * EMB);
    float sx = 0.f, sw = 0.f, sd = 0.f;
#pragma unroll
    for (int q = 0; q < 2; ++q) {
        float4 a = xr[lane * 2 + q];
        float4 b = wr[lane * 2 + q];
        sx += a.x*a.x + a.y*a.y + a.z*a.z + a.w*a.w;
        sw += b.x*b.x + b.y*b.y + b.z*b.z + b.w*b.w;
        sd += a.x*b.x + a.y*b.y + a.z*b.z + a.w*b.w;
    }
#pragma unroll
    for (int d = 1; d < 64; d <<= 1) {
        sx += __shfl_xor(sx, d);
        sw += __shfl_xor(sw, d);
        sd += __shfl_xor(sd, d);
    }
    if (lane == 0) {
        float cv = sd / (fmaxf(sqrtf(sx), 1e-12f) * fmaxf(sqrtf(sw), 1e-12f));
        float sine = sqrtf(fmaxf(0.f, 1.f - cv * cv));
        float phi  = cv * COS_M - sine * SIN_M;
        if (!(cv > TH_C)) phi = cv - MM_C;
        tcos[m] = S_SCALE * cv;
        tphi[m] = S_SCALE * phi;
    }
}

// ---------------------------------------------------------------------------
// Main kernel: producer/consumer wave specialization.
// 256 blocks x 1024 threads (16 waves, 1 block/CU):
//   waves 8..15 (producers): stream W chunk (ci+GRID) f32->regs (16 float4,
//     full MLP, no acc pressure), fold rn = S/||w|| into the bf16 pack,
//     swizzled ds_write into Bl[bb^1]. Tail classes -> zero rows (logit 0,
//     negligible vs LSE).
//   waves 0..7 (consumers): 64 rows x 64 classes MFMA on Bl[bb] (acc 64
//     regs, no staging pressure), epilogue merges 4 logits/lane across the
//     16 col-lanes and updates per-row online (M,S) in LDS msl[512].
// ONE barrier per chunk. Producer stalls never block consumers.
// ---------------------------------------------------------------------------
__global__ __launch_bounds__(1024, 4) void k_main(
        const float* __restrict__ W, const unsigned short* __restrict__ xb,
        float2* __restrict__ pms) {
    __shared__ __align__(16) unsigned short Bl[2][BN * EMB];  // 2 x 64 KiB
    __shared__ float2 msl[BATCH];                             // per-row (M,S)

    const int tid  = threadIdx.x;
    const int lane = tid & 63;
    const int wid  = tid >> 6;

    if (tid < BATCH) msl[tid] = make_float2(-1e38f, 0.0f);

    // ---------------- producer staging (waves 8..15) ----------------
    const int ptid = tid - 512;
    const int cc   = ptid >> 3;          // class within chunk (0..63)
    const int sj   = ptid & 7;           // 8 threads per class
    const float4* W4 = (const float4*)W;

    auto stageP = [&](int ci, int b) {
        int  c  = ci * BN + cc;
        bool ok = (c < NUM_CLASSES);
        const float4* src = W4 + (size_t)c * 128 + sj;
        float4 v[16];
        float4 z = make_float4(0.f, 0.f, 0.f, 0.f);
#pragma unroll
        for (int q = 0; q < 16; ++q) v[q] = ok ? src[8 * q] : z;
        float s = 0.f;
#pragma unroll
        for (int q = 0; q < 16; ++q)
            s += v[q].x*v[q].x + v[q].y*v[q].y + v[q].z*v[q].z + v[q].w*v[q].w;
        s += __shfl_xor(s, 1); s += __shfl_xor(s, 2); s += __shfl_xor(s, 4);
        float rn = ok ? S_SCALE / fmaxf(sqrtf(s), 1e-12f) : 0.0f;
        char* dst = (char*)&Bl[b][0] + cc * 1024;
#pragma unroll
        for (int q = 0; q < 16; ++q) {
            int fj = sj + 8 * q;
            *(uint2*)(dst + ((fj * 8) ^ ((cc & 7) << 4))) =
                make_uint2(f2bf(v[q].x * rn) | (f2bf(v[q].y * rn) << 16),
                           f2bf(v[q].z * rn) | (f2bf(v[q].w * rn) << 16));
        }
    };

    // ---------------- consumer geometry (waves 0..7) ----------------
    const int l15 = lane & 15;
    const int lg  = lane >> 4;
    const int sw  = (l15 & 7) << 4;
    const unsigned short* xp = xb + (size_t)(wid * 64 + l15) * EMB;

    // prologue: stage first chunk into buffer 0
    if (wid >= 8) stageP(blockIdx.x, 0);
    __syncthreads();

    int bb = 0;
    for (int ci = blockIdx.x; ci < NBLK; ci += GRID_MAIN) {
        if (wid >= 8) {
            int cn = ci + GRID_MAIN;
            if (cn < NBLK) stageP(cn, bb ^ 1);
        } else {
            // ---- MFMA k-loop: 64 rows x 64 classes per wave ----
            f4 acc[4][4];
#pragma unroll
            for (int mf = 0; mf < 4; ++mf)
#pragma unroll
                for (int nf = 0; nf < 4; ++nf)
#pragma unroll
                    for (int i = 0; i < 4; ++i) acc[mf][nf][i] = 0.0f;

            const char* BB = (const char*)&Bl[bb][0];
#pragma unroll 2
            for (int k0 = 0; k0 < EMB; k0 += 32) {
                int kb = k0 * 2 + lg * 16;
                bf8 b0 = *(const bf8*)(BB + (0 * 16 + l15) * 1024 + (kb ^ sw));
                bf8 b1 = *(const bf8*)(BB + (1 * 16 + l15) * 1024 + (kb ^ sw));
                bf8 b2 = *(const bf8*)(BB + (2 * 16 + l15) * 1024 + (kb ^ sw));
                bf8 b3 = *(const bf8*)(BB + (3 * 16 + l15) * 1024 + (kb ^ sw));
#pragma unroll
                for (int mf = 0; mf < 4; ++mf) {
                    bf8 a = *(const bf8*)(xp + mf * 16 * EMB + k0 + lg * 8);
                    acc[mf][0] = __builtin_amdgcn_mfma_f32_16x16x32_bf16(a, b0, acc[mf][0], 0, 0, 0);
                    acc[mf][1] = __builtin_amdgcn_mfma_f32_16x16x32_bf16(a, b1, acc[mf][1], 0, 0, 0);
                    acc[mf][2] = __builtin_amdgcn_mfma_f32_16x16x32_bf16(a, b2, acc[mf][2], 0, 0, 0);
                    acc[mf][3] = __builtin_amdgcn_mfma_f32_16x16x32_bf16(a, b3, acc[mf][3], 0, 0, 0);
                }
            }

            // ---- epilogue: logits (rn*S pre-baked) -> per-row online (M,S) ----
#pragma unroll
            for (int mf = 0; mf < 4; ++mf) {
                float mx[4], sm[4];
#pragma unroll
                for (int i = 0; i < 4; ++i)
                    mx[i] = fmaxf(fmaxf(acc[mf][0][i], acc[mf][1][i]),
                                  fmaxf(acc[mf][2][i], acc[mf][3][i]));
#pragma unroll
                for (int d = 1; d < 16; d <<= 1)
#pragma unroll
                    for (int i = 0; i < 4; ++i)
                        mx[i] = fmaxf(mx[i], __shfl_xor(mx[i], d));
#pragma unroll
                for (int i = 0; i < 4; ++i)
                    sm[i] = __expf(acc[mf][0][i] - mx[i]) + __expf(acc[mf][1][i] - mx[i])
                          + __expf(acc[mf][2][i] - mx[i]) + __expf(acc[mf][3][i] - mx[i]);
#pragma unroll
                for (int d = 1; d < 16; d <<= 1)
#pragma unroll
                    for (int i = 0; i < 4; ++i) sm[i] += __shfl_xor(sm[i], d);
                if (l15 == 0) {
#pragma unroll
                    for (int i = 0; i < 4; ++i) {
                        int m = wid * 64 + mf * 16 + lg * 4 + i;
                        float2 cur = msl[m];
                        float nM = fmaxf(cur.x, mx[i]);
                        msl[m] = make_float2(nM,
                            cur.y * __expf(cur.x - nM) + sm[i] * __expf(mx[i] - nM));
                    }
                }
            }
        }
        __syncthreads();
        bb ^= 1;
    }

    // one coalesced partial write per block
    if (tid < BATCH) pms[(size_t)blockIdx.x * BATCH + tid] = msl[tid];
}

// ---------------------------------------------------------------------------
// k_fin: merge 256 partials per row, patch label column (plain->margin),
// loss, mean -> out[0].
// ---------------------------------------------------------------------------
__global__ __launch_bounds__(512) void k_fin(const float2* __restrict__ pms,
                                             const float* __restrict__ tcos,
                                             const float* __restrict__ tphi,
                                             float* __restrict__ out) {
    int t = threadIdx.x;
    float M = -1e38f, S = 0.f;
    for (int b = 0; b < GRID_MAIN; ++b) {
        float2 v = pms[(size_t)b * BATCH + t];
        float nM = fmaxf(M, v.x);
        S = S * __expf(M - nM) + v.y * __expf(v.x - nM);
        M = nM;
    }
    // replace plain label logit with margin logit in the softmax sum
    float Sc = S - __expf(tcos[t] - M) + __expf(tphi[t] - M);
    Sc = fmaxf(Sc, 1e-30f);
    float loss = M + logf(Sc) - tphi[t];
#pragma unroll
    for (int d = 1; d < 64; d <<= 1) loss += __shfl_xor(loss, d);
    __shared__ float wred[8];
    if ((t & 63) == 0) wred[t >> 6] = loss;
    __syncthreads();
    if (t == 0) {
        float s = 0.f;
        for (int w = 0; w < 8; ++w) s += wred[w];
        out[0] = s / (float)BATCH;
    }
}

extern "C" void kernel_launch(void* const* d_in, const int* in_sizes, int n_in,
                              void* d_out, int out_size, void* d_ws, size_t ws_size,
                              hipStream_t stream) {
    const float*     x     = (const float*)d_in[0];
    const long long* label = (const long long*)d_in[1];
    const float*     W     = (const float*)d_in[2];
    float*           out   = (float*)d_out;

    // workspace layout (~1.6 MB)
    char* ws = (char*)d_ws;
    unsigned short* xb   = (unsigned short*)ws;            // 524288 B
    float*          tcos = (float*)(ws + 524288);          // 2048 B
    float*          tphi = (float*)(ws + 526336);          // 2048 B
    float2*         pms  = (float2*)(ws + 528384);         // 256*512*8 = 1048576 B

    k_normx<<<BATCH / 4, 256,  0, stream>>>(x, xb);
    k_tgt  <<<BATCH / 8, 512,  0, stream>>>(x, W, label, tcos, tphi);
    k_main <<<GRID_MAIN, 1024, 0, stream>>>(W, xb, pms);
    k_fin  <<<1,         512,  0, stream>>>(pms, tcos, tphi, out);
}

// Round 7
// 184.015 us; speedup vs baseline: 1.2031x; 1.2031x over previous
//
#include <hip/hip_runtime.h>
#include <math.h>

#define NUM_CLASSES 100000
#define EMB 512
#define BATCH 512
#define BN 64
#define NBLK ((NUM_CLASSES + BN - 1) / BN)   /* 1563 chunks of 64 classes */
#define GRID_MAIN 256                        /* persistent, 1 block/CU */

// ArcFace constants (margin m=0.3, scale s=120)
#define S_SCALE 120.0f
#define COS_M   0.9553364891256061f
#define SIN_M   0.29552020666133955f
#define TH_C   (-0.9553364891256061f)        /* cos(pi - m) */
#define MM_C    0.08865606199840187f         /* sin(pi - m) * m */

typedef short bf8 __attribute__((ext_vector_type(8)));   // 8 x bf16 (4 VGPRs)
typedef float f4  __attribute__((ext_vector_type(4)));   // MFMA accumulator

__device__ __forceinline__ unsigned short f2bf(float f) {
    union { float f; unsigned u; } a; a.f = f;
    unsigned r = a.u + 0x7fffu + ((a.u >> 16) & 1u);     // round-nearest-even
    return (unsigned short)(r >> 16);
}

// ---------------------------------------------------------------------------
// Kernel 1: L2-normalize rows of x (f32) -> bf16, one wave per row.
// ---------------------------------------------------------------------------
__global__ __launch_bounds__(256) void k_normx(const float* __restrict__ x,
                                               unsigned short* __restrict__ xb) {
    int row  = blockIdx.x * 4 + (threadIdx.x >> 6);
    int lane = threadIdx.x & 63;
    const float4* xr = (const float4*)(x + (size_t)row * EMB);
    float4 a = xr[lane * 2];
    float4 b = xr[lane * 2 + 1];
    float ss = a.x*a.x + a.y*a.y + a.z*a.z + a.w*a.w
             + b.x*b.x + b.y*b.y + b.z*b.z + b.w*b.w;
#pragma unroll
    for (int d = 1; d < 64; d <<= 1) ss += __shfl_xor(ss, d);
    float rn = 1.0f / fmaxf(sqrtf(ss), 1e-12f);
    int4 o;
    o.x = f2bf(a.x * rn) | (f2bf(a.y * rn) << 16);
    o.y = f2bf(a.z * rn) | (f2bf(a.w * rn) << 16);
    o.z = f2bf(b.x * rn) | (f2bf(b.y * rn) << 16);
    o.w = f2bf(b.z * rn) | (f2bf(b.w * rn) << 16);
    ((int4*)(xb + (size_t)row * EMB))[lane] = o;
}

// ---------------------------------------------------------------------------
// Kernel 2: exact f32 target logit per row: s*cos and s*phi at the label.
// ---------------------------------------------------------------------------
__global__ __launch_bounds__(512) void k_tgt(const float* __restrict__ x,
                                             const float* __restrict__ W,
                                             const long long* __restrict__ label,
                                             float* __restrict__ tcos,
                                             float* __restrict__ tphi) {
    int m    = blockIdx.x * 8 + (threadIdx.x >> 6);
    int lane = threadIdx.x & 63;
    int lb   = (int)label[m];
    const float4* xr = (const float4*)(x + (size_t)m  * EMB);
    const float4* wr = (const float4*)(W + (size_t)lb * EMB);
    float sx = 0.f, sw = 0.f, sd = 0.f;
#pragma unroll
    for (int q = 0; q < 2; ++q) {
        float4 a = xr[lane * 2 + q];
        float4 b = wr[lane * 2 + q];
        sx += a.x*a.x + a.y*a.y + a.z*a.z + a.w*a.w;
        sw += b.x*b.x + b.y*b.y + b.z*b.z + b.w*b.w;
        sd += a.x*b.x + a.y*b.y + a.z*b.z + a.w*b.w;
    }
#pragma unroll
    for (int d = 1; d < 64; d <<= 1) {
        sx += __shfl_xor(sx, d);
        sw += __shfl_xor(sw, d);
        sd += __shfl_xor(sd, d);
    }
    if (lane == 0) {
        float cv = sd / (fmaxf(sqrtf(sx), 1e-12f) * fmaxf(sqrtf(sw), 1e-12f));
        float sine = sqrtf(fmaxf(0.f, 1.f - cv * cv));
        float phi  = cv * COS_M - sine * SIN_M;
        if (!(cv > TH_C)) phi = cv - MM_C;
        tcos[m] = S_SCALE * cv;
        tphi[m] = S_SCALE * phi;
    }
}

// ---------------------------------------------------------------------------
// Main kernel: zero-VGPR staging via global_load_lds + in-place convert.
// 256 blocks x 1024 threads (16 waves, 1 block/CU). LDS: 128 KiB buffer.
// Per 64-class chunk:
//   [vmcnt(0); bar]  raw f32 chunk (linear [64][2048B]) is in LDS
//   read 32 f32/thread -> regs (+sumsq)           [bar]
//   issue BACK half of next chunk (dest 64..128K, region now dead)
//   in-place convert: cvt_pk_bf16 -> XOR-swizzled bf16 in front 64K;
//   ssq: 6 shuffles + 1 LDS atomic per wave per 8 rows  [lgkm; bar]
//   k-loop: wave = 32 rows x 64 cls, 16x16x32 bf16, acc[2][4]
//   epilogue: *S/||w||, tail mask, per-lane online (M,S) in regs
//   [bar]  issue FRONT half of next chunk (bf16 region now dead)
// Raw s_barrier + counted waits keep prefetch loads in flight across
// barriers (no __syncthreads vmcnt-drain). Margin handled in k_tgt/k_fin.
// ---------------------------------------------------------------------------
__global__ __launch_bounds__(1024, 4) void k_main(
        const float* __restrict__ W, const unsigned short* __restrict__ xb,
        float2* __restrict__ pms) {
    __shared__ __align__(16) char B32[BN * EMB * 4];   // 128 KiB
    __shared__ float ssq[BN];

    const int tid  = threadIdx.x;
    const int lane = tid & 63;
    const int wv   = tid >> 6;         // wave id 0..15; rows wv*32 .. +32
    const int l15  = lane & 15;
    const int lg   = lane >> 4;
    const int sw   = (l15 & 7) << 4;   // B-frag read swizzle
    const unsigned short* xp = xb + (size_t)(wv * 32 + l15) * EMB;

    // persistent per-lane online-softmax state
    float Mr[2][4], Sr[2][4];
#pragma unroll
    for (int mf = 0; mf < 2; ++mf)
#pragma unroll
        for (int i = 0; i < 4; ++i) { Mr[mf][i] = -1e38f; Sr[mf][i] = 0.0f; }

    // issue 4 of the 8 load-groups of chunk ci (qb=0: front 64K, qb=4: back)
    auto issue4 = [&](int ci, int qb) {
#pragma unroll
        for (int q = qb; q < qb + 4; ++q) {
            int unit = q * 1024 + tid;            // 16-B unit index in chunk
            int c    = ci * BN + (unit >> 7);     // global class of this unit
            if (c > NUM_CLASSES - 1) c = NUM_CLASSES - 1;   // tail clamp
            const char* src = (const char*)W + (size_t)c * (EMB * 4)
                            + (unit & 127) * 16;
            __builtin_amdgcn_global_load_lds(
                (const __attribute__((address_space(1))) unsigned int*)src,
                (__attribute__((address_space(3))) unsigned int*)
                    (B32 + q * 16384 + wv * 1024),
                16, 0, 0);
        }
    };

    issue4(blockIdx.x, 0);
    issue4(blockIdx.x, 4);

    for (int ci = blockIdx.x; ci < NBLK; ci += GRID_MAIN) {
        asm volatile("s_waitcnt vmcnt(0)" ::: "memory");
        __builtin_amdgcn_sched_barrier(0);
        __builtin_amdgcn_s_barrier();              // f32 chunk ready

        if (tid < BN) ssq[tid] = 0.0f;

        // ---- read 32 f32 -> regs (flat, lane-contiguous b128) ----
        const float4* Bf = (const float4*)B32;
        float4 r[8];
#pragma unroll
        for (int q = 0; q < 8; ++q) r[q] = Bf[q * 1024 + tid];
        float sq[8];
#pragma unroll
        for (int q = 0; q < 8; ++q)
            sq[q] = r[q].x*r[q].x + r[q].y*r[q].y + r[q].z*r[q].z + r[q].w*r[q].w;

        asm volatile("s_waitcnt lgkmcnt(0)" ::: "memory");
        __builtin_amdgcn_sched_barrier(0);
        __builtin_amdgcn_s_barrier();              // all reads done

        const bool has = (ci + GRID_MAIN) < NBLK;
        if (has) issue4(ci + GRID_MAIN, 4);        // prefetch back half

        // ---- in-place convert to swizzled bf16 (front 64K) ----
        const int kb = (tid & 127) * 8;            // bf16 byte-in-row
#pragma unroll
        for (int q = 0; q < 8; ++q) {
            int cls = q * 8 + (tid >> 7);
            unsigned lo, hi;
            asm("v_cvt_pk_bf16_f32 %0, %1, %2" : "=v"(lo) : "v"(r[q].x), "v"(r[q].y));
            asm("v_cvt_pk_bf16_f32 %0, %1, %2" : "=v"(hi) : "v"(r[q].z), "v"(r[q].w));
            *(uint2*)(B32 + cls * 1024 + (kb ^ ((cls & 7) << 4))) = make_uint2(lo, hi);
        }
        // ---- ssq: wave-reduce, one LDS atomic per wave per row-group ----
#pragma unroll
        for (int q = 0; q < 8; ++q) {
            float s = sq[q];
            s += __shfl_xor(s, 1);  s += __shfl_xor(s, 2);  s += __shfl_xor(s, 4);
            s += __shfl_xor(s, 8);  s += __shfl_xor(s, 16); s += __shfl_xor(s, 32);
            if (lane == 0) atomicAdd(&ssq[q * 8 + (tid >> 7)], s);
        }

        asm volatile("s_waitcnt lgkmcnt(0)" ::: "memory");
        __builtin_amdgcn_sched_barrier(0);
        __builtin_amdgcn_s_barrier();              // bf16 + ssq visible

        // ---- MFMA k-loop: 32 rows x 64 classes per wave ----
        f4 acc[2][4];
#pragma unroll
        for (int mf = 0; mf < 2; ++mf)
#pragma unroll
            for (int nf = 0; nf < 4; ++nf)
#pragma unroll
                for (int i = 0; i < 4; ++i) acc[mf][nf][i] = 0.0f;

#pragma unroll 4
        for (int k0 = 0; k0 < EMB; k0 += 32) {
            int kb2 = k0 * 2 + lg * 16;
            bf8 b0 = *(const bf8*)(B32 + (0 * 16 + l15) * 1024 + (kb2 ^ sw));
            bf8 b1 = *(const bf8*)(B32 + (1 * 16 + l15) * 1024 + (kb2 ^ sw));
            bf8 b2 = *(const bf8*)(B32 + (2 * 16 + l15) * 1024 + (kb2 ^ sw));
            bf8 b3 = *(const bf8*)(B32 + (3 * 16 + l15) * 1024 + (kb2 ^ sw));
            bf8 a0 = *(const bf8*)(xp + k0 + lg * 8);
            bf8 a1 = *(const bf8*)(xp + 16 * EMB + k0 + lg * 8);
            acc[0][0] = __builtin_amdgcn_mfma_f32_16x16x32_bf16(a0, b0, acc[0][0], 0, 0, 0);
            acc[0][1] = __builtin_amdgcn_mfma_f32_16x16x32_bf16(a0, b1, acc[0][1], 0, 0, 0);
            acc[0][2] = __builtin_amdgcn_mfma_f32_16x16x32_bf16(a0, b2, acc[0][2], 0, 0, 0);
            acc[0][3] = __builtin_amdgcn_mfma_f32_16x16x32_bf16(a0, b3, acc[0][3], 0, 0, 0);
            acc[1][0] = __builtin_amdgcn_mfma_f32_16x16x32_bf16(a1, b0, acc[1][0], 0, 0, 0);
            acc[1][1] = __builtin_amdgcn_mfma_f32_16x16x32_bf16(a1, b1, acc[1][1], 0, 0, 0);
            acc[1][2] = __builtin_amdgcn_mfma_f32_16x16x32_bf16(a1, b2, acc[1][2], 0, 0, 0);
            acc[1][3] = __builtin_amdgcn_mfma_f32_16x16x32_bf16(a1, b3, acc[1][3], 0, 0, 0);
        }

        // ---- epilogue: scale by S/||w||, tail mask, online (M,S) ----
        float rn[4];
#pragma unroll
        for (int nf = 0; nf < 4; ++nf)
            rn[nf] = S_SCALE / fmaxf(sqrtf(ssq[nf * 16 + l15]), 1e-12f);
        const int  c0   = ci * BN;
        const bool tail = (c0 + BN > NUM_CLASSES);
#pragma unroll
        for (int mf = 0; mf < 2; ++mf)
#pragma unroll
            for (int i = 0; i < 4; ++i) {
                float v0 = acc[mf][0][i] * rn[0];
                float v1 = acc[mf][1][i] * rn[1];
                float v2 = acc[mf][2][i] * rn[2];
                float v3 = acc[mf][3][i] * rn[3];
                if (tail) {
                    if (c0 + 0 * 16 + l15 >= NUM_CLASSES) v0 = -1e30f;
                    if (c0 + 1 * 16 + l15 >= NUM_CLASSES) v1 = -1e30f;
                    if (c0 + 2 * 16 + l15 >= NUM_CLASSES) v2 = -1e30f;
                    if (c0 + 3 * 16 + l15 >= NUM_CLASSES) v3 = -1e30f;
                }
                float pm = fmaxf(fmaxf(v0, v1), fmaxf(v2, v3));
                float nM = fmaxf(Mr[mf][i], pm);
                Sr[mf][i] = Sr[mf][i] * __expf(Mr[mf][i] - nM)
                          + __expf(v0 - nM) + __expf(v1 - nM)
                          + __expf(v2 - nM) + __expf(v3 - nM);
                Mr[mf][i] = nM;
            }

        __builtin_amdgcn_sched_barrier(0);
        __builtin_amdgcn_s_barrier();              // k-loop reads done
        if (has) issue4(ci + GRID_MAIN, 0);        // prefetch front half
    }

    // ---- final merge across the 16 column-lanes, one write per row ----
#pragma unroll
    for (int mf = 0; mf < 2; ++mf)
#pragma unroll
        for (int i = 0; i < 4; ++i) {
            float M = Mr[mf][i], S = Sr[mf][i];
#pragma unroll
            for (int d = 1; d < 16; d <<= 1) {
                float oM = __shfl_xor(M, d), oS = __shfl_xor(S, d);
                float nM = fmaxf(M, oM);
                S = S * __expf(M - nM) + oS * __expf(oM - nM);
                M = nM;
            }
            if (l15 == 0) {
                int m = wv * 32 + mf * 16 + lg * 4 + i;
                pms[(size_t)blockIdx.x * BATCH + m] = make_float2(M, S);
            }
        }
}

// ---------------------------------------------------------------------------
// k_fin: merge 256 partials per row, patch label column (plain->margin),
// loss, mean -> out[0].
// ---------------------------------------------------------------------------
__global__ __launch_bounds__(512) void k_fin(const float2* __restrict__ pms,
                                             const float* __restrict__ tcos,
                                             const float* __restrict__ tphi,
                                             float* __restrict__ out) {
    int t = threadIdx.x;
    float M = -1e38f, S = 0.f;
    for (int b = 0; b < GRID_MAIN; ++b) {
        float2 v = pms[(size_t)b * BATCH + t];
        float nM = fmaxf(M, v.x);
        S = S * __expf(M - nM) + v.y * __expf(v.x - nM);
        M = nM;
    }
    // replace plain label logit with margin logit in the softmax sum
    float Sc = S - __expf(tcos[t] - M) + __expf(tphi[t] - M);
    Sc = fmaxf(Sc, 1e-30f);
    float loss = M + logf(Sc) - tphi[t];
#pragma unroll
    for (int d = 1; d < 64; d <<= 1) loss += __shfl_xor(loss, d);
    __shared__ float wred[8];
    if ((t & 63) == 0) wred[t >> 6] = loss;
    __syncthreads();
    if (t == 0) {
        float s = 0.f;
        for (int w = 0; w < 8; ++w) s += wred[w];
        out[0] = s / (float)BATCH;
    }
}

extern "C" void kernel_launch(void* const* d_in, const int* in_sizes, int n_in,
                              void* d_out, int out_size, void* d_ws, size_t ws_size,
                              hipStream_t stream) {
    const float*     x     = (const float*)d_in[0];
    const long long* label = (const long long*)d_in[1];
    const float*     W     = (const float*)d_in[2];
    float*           out   = (float*)d_out;

    // workspace layout (~1.6 MB)
    char* ws = (char*)d_ws;
    unsigned short* xb   = (unsigned short*)ws;            // 524288 B
    float*          tcos = (float*)(ws + 524288);          // 2048 B
    float*          tphi = (float*)(ws + 526336);          // 2048 B
    float2*         pms  = (float2*)(ws + 528384);         // 256*512*8 = 1048576 B

    k_normx<<<BATCH / 4, 256,  0, stream>>>(x, xb);
    k_tgt  <<<BATCH / 8, 512,  0, stream>>>(x, W, label, tcos, tphi);
    k_main <<<GRID_MAIN, 1024, 0, stream>>>(W, xb, pms);
    k_fin  <<<1,         512,  0, stream>>>(pms, tcos, tphi, out);
}